// Round 2
// baseline (2779.728 us; speedup 1.0000x reference)
//
#include <hip/hip_runtime.h>

typedef unsigned short ushort_t;
typedef __attribute__((ext_vector_type(4))) float f32x4;
typedef __attribute__((ext_vector_type(8))) short s16x8;
typedef __attribute__((ext_vector_type(4))) unsigned short u16x4;
typedef __attribute__((ext_vector_type(8))) __bf16 bf16x8;

#define DEV __device__ __forceinline__

DEV float bf2f(ushort_t u){ union { unsigned int i; float f; } v; v.i = ((unsigned int)u) << 16; return v.f; }
DEV ushort_t f2bf(float f){
  union { float f; unsigned int i; } v; v.f = f;
  unsigned int r = v.i + 0x7FFFu + ((v.i >> 16) & 1u);   // RNE
  return (ushort_t)(r >> 16);
}
DEV float frcp(float x){
#if __has_builtin(__builtin_amdgcn_rcpf)
  return __builtin_amdgcn_rcpf(x);
#else
  return 1.0f / x;
#endif
}
DEV float fast_tanh(float x){
  x = fminf(9.0f, fmaxf(-9.0f, x));
  float e = __expf(2.0f * x);
  return fmaf(-2.0f, frcp(e + 1.0f), 1.0f);
}
DEV float fast_sig(float x){ return frcp(1.0f + __expf(-x)); }

DEV f32x4 mfma16(s16x8 a, s16x8 b, f32x4 c){
  return __builtin_amdgcn_mfma_f32_16x16x32_bf16(
      __builtin_bit_cast(bf16x8, a), __builtin_bit_cast(bf16x8, b), c, 0, 0, 0);
}

// ---------------------------------------------------------------------------
// Generic B^T GEMM: C[m,n] = sum_k A[m,k] * B[n,k].  64x64 block tile, BK=32,
// 4 waves in 2x2, each wave a 32x32 subtile via 16x16x32 bf16 MFMA.
// MODE 0: A=h f32 [16384,1024], B=W_attn2 f32 [1024,1024] -> z2 bf16 (+b_attn1[n]+b_attn2[n])
// MODE 1: A=ds bf16 [256,2048]; n<1024: B=Wa1 bf16 (K=2048); n>=1024: B=Whh bf16 (K=1024, uses d only)
//         -> out f32 [256,5120]
// MODE 2: A=dct bf16 [256,2048], B=W_fc1 f32 [1024,2048] -> out f32 [256,1024]
// ---------------------------------------------------------------------------
template<int MODE>
__global__ __launch_bounds__(256) void gemm_bt_k(
    const void* __restrict__ Ap, const void* __restrict__ Bp, const void* __restrict__ B2p,
    void* __restrict__ Cp, const float* __restrict__ bias1, const float* __restrict__ bias2)
{
  const int bm0 = blockIdx.x * 64;
  const int bn0 = blockIdx.y * 64;
  const int tid = threadIdx.x;
  const int srow = tid >> 2, sseg = tid & 3;
  const int wid = tid >> 6, lane = tid & 63;
  const int wr = wid >> 1, wc = wid & 1;
  const int fr = lane & 15, kseg = lane >> 4;

  int K;
  const float* Af = nullptr; const ushort_t* Ab = nullptr;
  const float* Bf = nullptr; const ushort_t* Bb = nullptr;
  if constexpr (MODE == 0) {
    K = 1024;
    Af = (const float*)Ap + (size_t)(bm0 + srow) * 1024;
    Bf = (const float*)Bp + (size_t)(bn0 + srow) * 1024;
  } else if constexpr (MODE == 1) {
    Ab = (const ushort_t*)Ap + (size_t)(bm0 + srow) * 2048;
    if (bn0 < 1024) { K = 2048; Bb = (const ushort_t*)Bp  + (size_t)(bn0 + srow) * 2048; }
    else            { K = 1024; Bb = (const ushort_t*)B2p + (size_t)(bn0 - 1024 + srow) * 1024; }
  } else {
    K = 2048;
    Ab = (const ushort_t*)Ap + (size_t)(bm0 + srow) * 2048;
    Bf = (const float*)Bp + (size_t)(bn0 + srow) * 2048;
  }

  __shared__ ushort_t As[64 * 32];
  __shared__ ushort_t Bs[64 * 32];
  f32x4 acc00 = {0,0,0,0}, acc01 = {0,0,0,0}, acc10 = {0,0,0,0}, acc11 = {0,0,0,0};

  // XOR-swizzled 16B slots to tame ds_read_b128 bank conflicts
  const int sstore = srow * 32 + ((sseg ^ (srow & 3)) << 3);
  const int ar0 = wr * 32 + fr,      ar1 = wr * 32 + 16 + fr;
  const int br0 = wc * 32 + fr,      br1 = wc * 32 + 16 + fr;
  const int aoff0 = ar0 * 32 + ((kseg ^ (ar0 & 3)) << 3);
  const int aoff1 = ar1 * 32 + ((kseg ^ (ar1 & 3)) << 3);
  const int boff0 = br0 * 32 + ((kseg ^ (br0 & 3)) << 3);
  const int boff1 = br1 * 32 + ((kseg ^ (br1 & 3)) << 3);

  for (int k0 = 0; k0 < K; k0 += 32) {
    s16x8 av, bv;
    if constexpr (MODE == 0) {
      const float* p = Af + k0 + sseg * 8;
      f32x4 x0 = *(const f32x4*)p, x1 = *(const f32x4*)(p + 4);
      av[0]=(short)f2bf(x0[0]); av[1]=(short)f2bf(x0[1]); av[2]=(short)f2bf(x0[2]); av[3]=(short)f2bf(x0[3]);
      av[4]=(short)f2bf(x1[0]); av[5]=(short)f2bf(x1[1]); av[6]=(short)f2bf(x1[2]); av[7]=(short)f2bf(x1[3]);
    } else {
      av = *(const s16x8*)(Ab + k0 + sseg * 8);
    }
    if constexpr (MODE == 0 || MODE == 2) {
      const float* p = Bf + k0 + sseg * 8;
      f32x4 x0 = *(const f32x4*)p, x1 = *(const f32x4*)(p + 4);
      bv[0]=(short)f2bf(x0[0]); bv[1]=(short)f2bf(x0[1]); bv[2]=(short)f2bf(x0[2]); bv[3]=(short)f2bf(x0[3]);
      bv[4]=(short)f2bf(x1[0]); bv[5]=(short)f2bf(x1[1]); bv[6]=(short)f2bf(x1[2]); bv[7]=(short)f2bf(x1[3]);
    } else {
      bv = *(const s16x8*)(Bb + k0 + sseg * 8);
    }
    *(s16x8*)&As[sstore] = av;
    *(s16x8*)&Bs[sstore] = bv;
    __syncthreads();
    s16x8 a0 = *(const s16x8*)&As[aoff0];
    s16x8 a1 = *(const s16x8*)&As[aoff1];
    s16x8 b0 = *(const s16x8*)&Bs[boff0];
    s16x8 b1 = *(const s16x8*)&Bs[boff1];
    acc00 = mfma16(a0, b0, acc00);
    acc01 = mfma16(a0, b1, acc01);
    acc10 = mfma16(a1, b0, acc10);
    acc11 = mfma16(a1, b1, acc11);
    __syncthreads();
  }

  const int mbase = bm0 + wr * 32 + kseg * 4;   // C/D: row=(lane>>4)*4+r, col=lane&15
  const int nbase = bn0 + wc * 32 + fr;
  auto wr4 = [&](f32x4 v, int m0, int n0) {
    #pragma unroll
    for (int r = 0; r < 4; ++r) {
      float x = v[r];
      if constexpr (MODE == 0)
        ((ushort_t*)Cp)[(size_t)(m0 + r) * 1024 + n0] = f2bf(x + bias1[n0] + bias2[n0]);
      else if constexpr (MODE == 1)
        ((float*)Cp)[(size_t)(m0 + r) * 5120 + n0] = x;
      else
        ((float*)Cp)[(size_t)(m0 + r) * 1024 + n0] = x;
    }
  };
  wr4(acc00, mbase,      nbase);
  wr4(acc01, mbase,      nbase + 16);
  wr4(acc10, mbase + 16, nbase);
  wr4(acc11, mbase + 16, nbase + 16);
}

// ---------------------------------------------------------------------------
// Fused per-step: z3 = sum_c tanh(z1[b,c]+z2'[b,t,c])*wa3[c]; softmax over t;
// y_tilde via precomputed htw; then the LSTM pointwise update in-block.
// One block per b (512 threads = 8 waves; wave w handles t = w*8..w*8+7).
// FINAL=1: write beta, skip LSTM.
// ---------------------------------------------------------------------------
template<int FINAL>
__global__ __launch_bounds__(512) void attn_step_k(
    const float* __restrict__ z1g, const ushort_t* __restrict__ z2bf,
    const float* __restrict__ htw, const float* __restrict__ wa3,
    const float* __restrict__ y_seq, const float* __restrict__ Wt,
    const float* __restrict__ btld, const float* __restrict__ W_ih,
    const float* __restrict__ b_ih, const float* __restrict__ b_hh,
    float* __restrict__ s_st, ushort_t* __restrict__ ds_bf,
    float* __restrict__ beta_out, int t_step)
{
  const int b = blockIdx.x;
  const int tid = threadIdx.x;
  const int w = tid >> 6, lane = tid & 63;

  float z1c[16], wc3[16];
  {
    const float* zp = z1g + (size_t)b * 5120 + lane * 16;
    const float* wp = wa3 + lane * 16;
    #pragma unroll
    for (int j = 0; j < 16; j += 4) {
      f32x4 a = *(const f32x4*)(zp + j);
      f32x4 c = *(const f32x4*)(wp + j);
      z1c[j]=a[0]; z1c[j+1]=a[1]; z1c[j+2]=a[2]; z1c[j+3]=a[3];
      wc3[j]=c[0]; wc3[j+1]=c[1]; wc3[j+2]=c[2]; wc3[j+3]=c[3];
    }
  }

  __shared__ float zs[64];
  __shared__ float yt_sh;

  #pragma unroll
  for (int i = 0; i < 8; ++i) {
    const int t = w * 8 + i;
    const ushort_t* zp = z2bf + (((size_t)(b * 64 + t)) << 10) + lane * 16;
    s16x8 v0 = *(const s16x8*)zp;
    s16x8 v1 = *(const s16x8*)(zp + 8);
    float acc = 0.0f;
    #pragma unroll
    for (int j = 0; j < 8; ++j) acc = fmaf(fast_tanh(z1c[j]     + bf2f((ushort_t)v0[j])), wc3[j],     acc);
    #pragma unroll
    for (int j = 0; j < 8; ++j) acc = fmaf(fast_tanh(z1c[8 + j] + bf2f((ushort_t)v1[j])), wc3[8 + j], acc);
    #pragma unroll
    for (int m = 32; m >= 1; m >>= 1) acc += __shfl_xor(acc, m);
    if (lane == 0) zs[t] = acc;
  }
  __syncthreads();

  if (w == 0) {
    float v = zs[lane];
    float mx = v;
    #pragma unroll
    for (int m = 32; m >= 1; m >>= 1) mx = fmaxf(mx, __shfl_xor(mx, m));
    float e = __expf(v - mx);
    float sum = e;
    #pragma unroll
    for (int m = 32; m >= 1; m >>= 1) sum += __shfl_xor(sum, m);
    float betav = e * frcp(sum);
    if constexpr (FINAL) beta_out[b * 64 + lane] = betav;
    float a = betav * htw[b * 64 + lane];
    #pragma unroll
    for (int m = 32; m >= 1; m >>= 1) a += __shfl_xor(a, m);
    if (lane == 0) yt_sh = fmaf(Wt[0], y_seq[b * 64 + t_step], a + btld[0]);
  }
  __syncthreads();
  if constexpr (FINAL) return;

  const float ytv = yt_sh;
  const float* zb = z1g + (size_t)b * 5120;
  #pragma unroll
  for (int r = 0; r < 2; ++r) {
    const int hi = tid + r * 512;
    float gi = zb[1024 + hi] + ytv * W_ih[hi]        + b_ih[hi]        + b_hh[hi];
    float gf = zb[2048 + hi] + ytv * W_ih[1024 + hi] + b_ih[1024 + hi] + b_hh[1024 + hi];
    float gg = zb[3072 + hi] + ytv * W_ih[2048 + hi] + b_ih[2048 + hi] + b_hh[2048 + hi];
    float go = zb[4096 + hi] + ytv * W_ih[3072 + hi] + b_ih[3072 + hi] + b_hh[3072 + hi];
    float so = s_st[(size_t)b * 1024 + hi];
    float ig = fast_sig(gi), fg = fast_sig(gf), gt = fast_tanh(gg), og = fast_sig(go);
    float sn = fmaf(fg, so, ig * gt);
    float dn = og * fast_tanh(sn);
    s_st[(size_t)b * 1024 + hi] = sn;
    ds_bf[(size_t)b * 2048 + hi] = f2bf(dn);
    ds_bf[(size_t)b * 2048 + 1024 + hi] = f2bf(sn);
  }
}

// htw[b,t] = sum_c h[b,t,c] * W_tilde[1+c]
__global__ __launch_bounds__(256) void htw_k(const float* __restrict__ h, const float* __restrict__ Wt,
                                             float* __restrict__ htw)
{
  const int btx = blockIdx.x;
  const int tid = threadIdx.x;
  const float* hp = h + ((size_t)btx << 10);
  const int c = tid * 4;
  f32x4 hv = *(const f32x4*)(hp + c);
  float acc = hv[0]*Wt[1+c] + hv[1]*Wt[2+c] + hv[2]*Wt[3+c] + hv[3]*Wt[4+c];
  #pragma unroll
  for (int m = 32; m >= 1; m >>= 1) acc += __shfl_xor(acc, m);
  __shared__ float red[4];
  if ((tid & 63) == 0) red[tid >> 6] = acc;
  __syncthreads();
  if (tid == 0) htw[btx] = red[0] + red[1] + red[2] + red[3];
}

// ct[b,c] = sum_t beta[b,t]*h[b,t,c]; also assemble dct = [d | ct] in bf16
__global__ __launch_bounds__(256) void ct_k(const float* __restrict__ h, const float* __restrict__ beta,
                                            const ushort_t* __restrict__ ds_bf, ushort_t* __restrict__ dct)
{
  const int bid = blockIdx.x;        // 1024 blocks
  const int b = bid >> 2, cb = bid & 3;
  const int c = cb * 256 + threadIdx.x;
  const float* hp = h + ((size_t)b << 16) + c;
  const float* bp = beta + b * 64;
  float acc = 0.0f;
  #pragma unroll 8
  for (int t = 0; t < 64; ++t) acc = fmaf(bp[t], hp[(size_t)t << 10], acc);
  dct[(size_t)b * 2048 + 1024 + c] = f2bf(acc);
  dct[(size_t)b * 2048 + c] = ds_bf[(size_t)b * 2048 + c];
}

// y[b] = sum_n (state[b,n]+b_fc1[n]) * W_fc2[n] + b_fc2   (f32 output!)
__global__ __launch_bounds__(256) void head2_k(const float* __restrict__ state, const float* __restrict__ b_fc1,
                                               const float* __restrict__ W_fc2, const float* __restrict__ b_fc2,
                                               float* __restrict__ out)
{
  const int b = blockIdx.x, tid = threadIdx.x;
  const int c = tid * 4;
  f32x4 sv = *(const f32x4*)(state + ((size_t)b << 10) + c);
  f32x4 bv = *(const f32x4*)(b_fc1 + c);
  f32x4 wv = *(const f32x4*)(W_fc2 + c);
  float acc = (sv[0]+bv[0])*wv[0] + (sv[1]+bv[1])*wv[1] + (sv[2]+bv[2])*wv[2] + (sv[3]+bv[3])*wv[3];
  #pragma unroll
  for (int m = 32; m >= 1; m >>= 1) acc += __shfl_xor(acc, m);
  __shared__ float red[4];
  if ((tid & 63) == 0) red[tid >> 6] = acc;
  __syncthreads();
  if (tid == 0) out[b] = red[0] + red[1] + red[2] + red[3] + b_fc2[0];
}

__global__ void cvt_k(const float* __restrict__ in, ushort_t* __restrict__ out, int n)
{
  int i = (blockIdx.x * blockDim.x + threadIdx.x) * 4;
  const int stride = gridDim.x * blockDim.x * 4;
  for (; i < n; i += stride) {
    f32x4 v = *(const f32x4*)(in + i);
    u16x4 o; o[0] = f2bf(v[0]); o[1] = f2bf(v[1]); o[2] = f2bf(v[2]); o[3] = f2bf(v[3]);
    *(u16x4*)(out + i) = o;
  }
}

extern "C" void kernel_launch(void* const* d_in, const int* in_sizes, int n_in,
                              void* d_out, int out_size, void* d_ws, size_t ws_size,
                              hipStream_t stream)
{
  const float* h       = (const float*)d_in[0];
  const float* y_seq   = (const float*)d_in[1];
  const float* W_attn1 = (const float*)d_in[2];
  const float* b_attn1 = (const float*)d_in[3];
  const float* W_attn2 = (const float*)d_in[4];
  const float* b_attn2 = (const float*)d_in[5];
  const float* W_attn3 = (const float*)d_in[6];
  // d_in[7] = b_attn3: softmax shift-invariant, unused
  const float* W_ih    = (const float*)d_in[8];
  const float* W_hh    = (const float*)d_in[9];
  const float* b_ih    = (const float*)d_in[10];
  const float* b_hh    = (const float*)d_in[11];
  const float* W_tilde = (const float*)d_in[12];
  const float* b_tilde = (const float*)d_in[13];
  const float* W_fc1   = (const float*)d_in[14];
  const float* b_fc1   = (const float*)d_in[15];
  const float* W_fc2   = (const float*)d_in[16];
  const float* b_fc2   = (const float*)d_in[17];
  (void)in_sizes; (void)n_in; (void)out_size; (void)ws_size;

  char* ws = (char*)d_ws;
  ushort_t* z2bf   = (ushort_t*)(ws + 0);          // 33554432 B: z2+b_attn1+b_attn2, bf16 [16384,1024]
  ushort_t* wa1bf  = (ushort_t*)(ws + 33554432);   //  4194304 B
  ushort_t* whhbf  = (ushort_t*)(ws + 37748736);   //  8388608 B
  float*    z1g    = (float*)   (ws + 46137344);   //  5242880 B: [256,5120] = [z1 | d@Whh^T]
  ushort_t* dsbf   = (ushort_t*)(ws + 51380224);   //  1048576 B: [256,2048] = [d | s] bf16
  float*    sst    = (float*)   (ws + 52428800);   //  1048576 B: s f32 master
  float*    htwp   = (float*)   (ws + 53477376);   //    65536 B
  float*    betap  = (float*)   (ws + 53542912);   //    65536 B
  ushort_t* dctp   = (ushort_t*)(ws + 53608448);   //  1048576 B
  float*    statep = (float*)   (ws + 54657024);   //  1048576 B

  hipMemsetAsync(dsbf, 0, 1048576, stream);
  hipMemsetAsync(sst,  0, 1048576, stream);
  cvt_k<<<dim3(256), dim3(256), 0, stream>>>(W_attn1, wa1bf, 2097152);
  cvt_k<<<dim3(256), dim3(256), 0, stream>>>(W_hh,    whhbf, 4194304);
  htw_k<<<dim3(16384), dim3(256), 0, stream>>>(h, W_tilde, htwp);
  gemm_bt_k<0><<<dim3(256, 16), dim3(256), 0, stream>>>(h, W_attn2, nullptr, z2bf, b_attn1, b_attn2);

  for (int t = 0; t < 63; ++t) {
    gemm_bt_k<1><<<dim3(4, 80), dim3(256), 0, stream>>>(dsbf, wa1bf, whhbf, z1g, nullptr, nullptr);
    attn_step_k<0><<<dim3(256), dim3(512), 0, stream>>>(z1g, z2bf, htwp, W_attn3, y_seq, W_tilde, b_tilde,
                                                        W_ih, b_ih, b_hh, sst, dsbf, nullptr, t);
  }

  // final attention (no LSTM update): only z1 needed -> grid.y = 16
  gemm_bt_k<1><<<dim3(4, 16), dim3(256), 0, stream>>>(dsbf, wa1bf, whhbf, z1g, nullptr, nullptr);
  attn_step_k<1><<<dim3(256), dim3(512), 0, stream>>>(z1g, z2bf, htwp, W_attn3, y_seq, W_tilde, b_tilde,
                                                      W_ih, b_ih, b_hh, sst, dsbf, betap, 63);
  ct_k<<<dim3(1024), dim3(256), 0, stream>>>(h, betap, dsbf, dctp);
  gemm_bt_k<2><<<dim3(4, 16), dim3(256), 0, stream>>>(dctp, W_fc1, nullptr, statep, nullptr, nullptr);
  head2_k<<<dim3(256), dim3(256), 0, stream>>>(statep, b_fc1, W_fc2, b_fc2, (float*)d_out);
}